// Round 6
// baseline (65.465 us; speedup 1.0000x reference)
//
#include <hip/hip_runtime.h>
#include <math.h>

typedef unsigned short ushort;
typedef unsigned int uint;

#define B 4
#define C 64
#define H 64
#define W 64
#define HW 4096
#define NEG 256
#define CHUNK_P 8
#define NCHUNK (HW / CHUNK_P)   // 512
#define NGRP 16
#define CHPG (NCHUNK / NGRP)    // 32

// ---------------- ws layout (float units) ----------------
#define OFF_Z2T     0
#define OFF_N1MAP   (OFF_Z2T + B*HW*32)
#define OFF_IMGT4   (OFF_N1MAP + B*HW)
#define OFF_PARTIAL (OFF_IMGT4 + HW*4)
#define OFF_PART2   (OFF_PARTIAL + B*NCHUNK*NEG)
#define OFF_PERB    (OFF_PART2 + B*NGRP*NEG)

typedef _Float16 h2_t __attribute__((ext_vector_type(2)));

__device__ __forceinline__ uint packf16(float a, float b) {
    _Float16 lo = (_Float16)a;
    _Float16 hi = (_Float16)b;
    return (uint)__builtin_bit_cast(unsigned short, lo) |
           ((uint)__builtin_bit_cast(unsigned short, hi) << 16);
}

__device__ __forceinline__ float dot2(uint a, uint b, float c) {
#if __has_builtin(__builtin_amdgcn_fdot2)
    return __builtin_amdgcn_fdot2(__builtin_bit_cast(h2_t, a),
                                  __builtin_bit_cast(h2_t, b), c, false);
#else
    h2_t x = __builtin_bit_cast(h2_t, a);
    h2_t y = __builtin_bit_cast(h2_t, b);
    return c + (float)x[0] * (float)y[0] + (float)x[1] * (float)y[1];
#endif
}

// quad_perm DPP cross-lane adds (lanes within group of 4); VALU, no DS pipe.
__device__ __forceinline__ float dpp_xor1(float x) {
#if __has_builtin(__builtin_amdgcn_update_dpp)
    return __int_as_float(__builtin_amdgcn_update_dpp(0, __float_as_int(x),
                                                      0xB1, 0xF, 0xF, true));
#else
    return __shfl_xor(x, 1);
#endif
}
__device__ __forceinline__ float dpp_xor2(float x) {
#if __has_builtin(__builtin_amdgcn_update_dpp)
    return __int_as_float(__builtin_amdgcn_update_dpp(0, __float_as_int(x),
                                                      0x4E, 0xF, 0xF, true));
#else
    return __shfl_xor(x, 2);
#endif
}

// Transpose views_2 (C,HW) -> z2th (HW,C) f16, columns pre-divided by their norm.
__global__ __launch_bounds__(256) void k_prep_z2(const float* __restrict__ v2,
                                                 ushort* __restrict__ z2th) {
    __shared__ float tile[64][65];
    __shared__ float npart[4][64];
    __shared__ float ninv[64];
    int b  = blockIdx.x >> 6;
    int q0 = (blockIdx.x & 63) * 64;
    int t  = threadIdx.x;
    int qq = t & 63;
    int cg = t >> 6;
    const float* src = v2 + (size_t)b * C * HW;
    float acc = 0.f;
#pragma unroll
    for (int r = 0; r < 16; ++r) {
        int c = cg * 16 + r;
        float v = src[(size_t)c * HW + q0 + qq];
        tile[c][qq] = v;
        acc += v * v;
    }
    npart[cg][qq] = acc;
    __syncthreads();
    if (t < 64) {
        float s = npart[0][t] + npart[1][t] + npart[2][t] + npart[3][t];
        ninv[t] = 1.0f / fmaxf(sqrtf(s), 1e-8f);
    }
    __syncthreads();
    int qw = t >> 2;
    int c0 = (t & 3) * 16;
    float inv = ninv[qw];
    uint us[8];
#pragma unroll
    for (int j = 0; j < 8; ++j)
        us[j] = packf16(tile[c0 + 2*j][qw] * inv, tile[c0 + 2*j + 1][qw] * inv);
    uint4* dst = (uint4*)(z2th + ((size_t)(b * HW + q0 + qw)) * 64 + c0);
    dst[0] = make_uint4(us[0], us[1], us[2], us[3]);
    dst[1] = make_uint4(us[4], us[5], us[6], us[7]);
}

// n1map (per-pixel norm of views_1) + img as float4 table.
__global__ __launch_bounds__(256) void k_prep_z1(const float* __restrict__ v1,
                                                 const float* __restrict__ img,
                                                 float* __restrict__ n1map,
                                                 float* __restrict__ imgt4) {
    int b = blockIdx.x >> 4;
    int q = (blockIdx.x & 15) * 256 + threadIdx.x;
    const float* src = v1 + (size_t)b * C * HW + q;
    float acc = 0.f;
#pragma unroll 8
    for (int c = 0; c < C; ++c) {
        float v = src[(size_t)c * HW];
        acc += v * v;
    }
    n1map[b * HW + q] = sqrtf(acc);
    if (b == 0) {
        float4 ip = make_float4(img[q], img[HW + q], img[2 * HW + q], 0.f);
        *(float4*)(imgt4 + q * 4) = ip;
    }
}

// Main: block = (b, 8 pixels). Phase A: {q byte-offset, w} per (pp,k) into LDS.
// Phase B: 2-pixel software pipeline, 16 gathers in flight, DPP reduce.
__global__ __launch_bounds__(256, 4) void k_main(const float* __restrict__ v1,
                                                 const int* __restrict__ negh,
                                                 const int* __restrict__ negw,
                                                 const ushort* __restrict__ z2th,
                                                 const float* __restrict__ n1map,
                                                 const float* __restrict__ imgt4,
                                                 float* __restrict__ partial) {
    __shared__ __align__(16) uint z1p[CHUNK_P][36];     // packed f16 pairs
    __shared__ __align__(16) uint2 qw_lds[CHUNK_P][64][4]; // [pixel][kk][g] = {qoff, wbits}
    __shared__ float4 imgps[CHUNK_P];
    int b     = blockIdx.x >> 9;
    int chunk = blockIdx.x & 511;
    int p0    = chunk * CHUNK_P;
    int t     = threadIdx.x;

    {   // stage z1 columns, normalized + packed f16
        int c2 = t >> 3;
        int pp = t & 7;
        const float* srcb = v1 + (size_t)b * C * HW;
        float inv = 1.0f / fmaxf(n1map[b * HW + p0 + pp], 1e-8f);
        float a0 = srcb[(size_t)(2 * c2)     * HW + p0 + pp] * inv;
        float a1 = srcb[(size_t)(2 * c2 + 1) * HW + p0 + pp] * inv;
        z1p[pp][c2] = packf16(a0, a1);
    }
    if (t < CHUNK_P) imgps[t] = *(const float4*)(imgt4 + (p0 + t) * 4);
    __syncthreads();

    const float inv_max_euc = 1.0f / sqrtf((float)((H - 1) * (H - 1) + (W - 1) * (W - 1)));
    const float inv_sqrt3   = 0.57735026919f;
    const int* nh = negh + ((size_t)b * HW + p0) * NEG + t;
    const int* nw = negw + ((size_t)b * HW + p0) * NEG + t;

    // Phase A: thread t = k index; store q byte-offset (q*128) and w.
#pragma unroll
    for (int pp = 0; pp < CHUNK_P; ++pp) {
        int p = p0 + pp;
        int ih = nh[pp * NEG];
        int iw = nw[pp * NEG];
        int qv = (ih << 6) + iw;
        float dh = (float)(p >> 6) - (float)ih;
        float dw = (float)(p & 63) - (float)iw;
        float euc = sqrtf(dh * dh + dw * dw) * inv_max_euc;
        float4 iq = *(const float4*)(imgt4 + qv * 4);
        float4 ip = imgps[pp];
        float dr = ip.x - iq.x, dg = ip.y - iq.y, db = ip.z - iq.z;
        float rgb = sqrtf(dr * dr + dg * dg + db * db) * inv_sqrt3;
        float wv = 0.8f * euc + 0.2f * rgb;
        qw_lds[pp][t & 63][t >> 6] = make_uint2((uint)(qv << 7), __float_as_uint(wv));
    }
    __syncthreads();

    // Phase B
    int c4 = t & 3;
    int kk = t >> 2;
    const char* z2base = (const char*)z2th + (size_t)b * HW * 128;
    float acc = 0.f;

    auto colsim = [&](uint4 A, uint4 Bv, uint4 u0, uint4 u1, uint wbits) -> float {
        float dA = 0.f, dB = 0.f;
        dA = dot2(A.x,  u0.x, dA); dA = dot2(A.y,  u0.y, dA);
        dA = dot2(A.z,  u0.z, dA); dA = dot2(A.w,  u0.w, dA);
        dB = dot2(Bv.x, u1.x, dB); dB = dot2(Bv.y, u1.y, dB);
        dB = dot2(Bv.z, u1.z, dB); dB = dot2(Bv.w, u1.w, dB);
        float d = dA + dB;
        d += dpp_xor1(d);
        d += dpp_xor2(d);
        return fminf(fabsf(d * __uint_as_float(wbits)), 1.0f);
    };

#pragma unroll
    for (int pp = 0; pp < CHUNK_P; pp += 2) {
        uint4 qw01 = *(const uint4*)&qw_lds[pp][kk][0];
        uint4 qw23 = *(const uint4*)&qw_lds[pp][kk][2];
        uint4 qw45 = *(const uint4*)&qw_lds[pp + 1][kk][0];
        uint4 qw67 = *(const uint4*)&qw_lds[pp + 1][kk][2];
        const uint4* c0p = (const uint4*)(z2base + qw01.x);
        const uint4* c1p = (const uint4*)(z2base + qw01.z);
        const uint4* c2p = (const uint4*)(z2base + qw23.x);
        const uint4* c3p = (const uint4*)(z2base + qw23.z);
        const uint4* c4p = (const uint4*)(z2base + qw45.x);
        const uint4* c5p = (const uint4*)(z2base + qw45.z);
        const uint4* c6p = (const uint4*)(z2base + qw67.x);
        const uint4* c7p = (const uint4*)(z2base + qw67.z);
        uint4 A0 = c0p[c4], B0 = c0p[4 + c4];
        uint4 A1 = c1p[c4], B1 = c1p[4 + c4];
        uint4 A2 = c2p[c4], B2 = c2p[4 + c4];
        uint4 A3 = c3p[c4], B3 = c3p[4 + c4];
        uint4 A4 = c4p[c4], B4 = c4p[4 + c4];
        uint4 A5 = c5p[c4], B5 = c5p[4 + c4];
        uint4 A6 = c6p[c4], B6 = c6p[4 + c4];
        uint4 A7 = c7p[c4], B7 = c7p[4 + c4];
        const uint4* z1a = (const uint4*)(&z1p[pp][0]);
        uint4 ua0 = z1a[c4], ua1 = z1a[4 + c4];
        const uint4* z1b = (const uint4*)(&z1p[pp + 1][0]);
        uint4 ub0 = z1b[c4], ub1 = z1b[4 + c4];

        float s0 = colsim(A0, B0, ua0, ua1, qw01.y);
        float s1 = colsim(A1, B1, ua0, ua1, qw01.w);
        float s2 = colsim(A2, B2, ua0, ua1, qw23.y);
        float s3 = colsim(A3, B3, ua0, ua1, qw23.w);
        float s4 = colsim(A4, B4, ub0, ub1, qw45.y);
        float s5 = colsim(A5, B5, ub0, ub1, qw45.w);
        float s6 = colsim(A6, B6, ub0, ub1, qw67.y);
        float s7 = colsim(A7, B7, ub0, ub1, qw67.w);
        acc += (c4 == 0) ? (s0 + s4) : 0.f;
        acc += (c4 == 1) ? (s1 + s5) : 0.f;
        acc += (c4 == 2) ? (s2 + s6) : 0.f;
        acc += (c4 == 3) ? (s3 + s7) : 0.f;
    }
    partial[((size_t)b * NCHUNK + chunk) * NEG + (c4 << 6) + kk] = acc;
}

// Stage-1 reduce: sum 32 chunks per group.
__global__ __launch_bounds__(256) void k_reduce1(const float* __restrict__ partial,
                                                 float* __restrict__ partial2) {
    int b = blockIdx.x >> 4;
    int g = blockIdx.x & 15;
    int t = threadIdx.x;
    float s = 0.f;
#pragma unroll 4
    for (int ch = 0; ch < CHPG; ++ch)
        s += partial[((size_t)b * NCHUNK + g * CHPG + ch) * NEG + t];
    partial2[((size_t)b * NGRP + g) * NEG + t] = s;
}

// Stage-2: per-item sneg[k], log terms, s0, bce.
__global__ __launch_bounds__(256) void k_reduce2(const float* __restrict__ partial2,
                                                 const float* __restrict__ n1map,
                                                 float* __restrict__ perb) {
    __shared__ float red[256];
    int b = blockIdx.x;
    int t = threadIdx.x;
    float s = 0.f;
#pragma unroll
    for (int g = 0; g < NGRP; ++g)
        s += partial2[((size_t)b * NGRP + g) * NEG + t];
    float sneg = s * (1.0f / HW) * 0.5f;
    float l1m  = fmaxf(logf(1.0f - sneg), -100.0f);
    float ss = 0.f;
#pragma unroll
    for (int j = 0; j < HW / 256; ++j) {
        float n1 = n1map[b * HW + j * 256 + t];
        float n1sq = n1 * n1;
        ss += fminf(n1sq / fmaxf(n1sq, 1e-8f), 1.0f);
    }
    float snegsum, l1msum, sssum;
    red[t] = sneg; __syncthreads();
    for (int sft = 128; sft > 0; sft >>= 1) { if (t < sft) red[t] += red[t + sft]; __syncthreads(); }
    snegsum = red[0]; __syncthreads();
    red[t] = l1m; __syncthreads();
    for (int sft = 128; sft > 0; sft >>= 1) { if (t < sft) red[t] += red[t + sft]; __syncthreads(); }
    l1msum = red[0]; __syncthreads();
    red[t] = ss; __syncthreads();
    for (int sft = 128; sft > 0; sft >>= 1) { if (t < sft) red[t] += red[t + sft]; __syncthreads(); }
    sssum = red[0];
    if (t == 0) {
        float s0  = sssum * (1.0f / HW);
        float bce = -(fmaxf(logf(s0), -100.0f) + l1msum) * (1.0f / (NEG + 1));
        perb[b * 3 + 0] = bce;
        perb[b * 3 + 1] = s0;
        perb[b * 3 + 2] = snegsum;
    }
}

__global__ void k_final(const float* __restrict__ perb, float* __restrict__ out) {
    if (threadIdx.x == 0 && blockIdx.x == 0) {
        float bsum = 0.f, s0sum = 0.f, snegsum = 0.f;
        for (int b = 0; b < B; ++b) {
            bsum    += perb[b * 3 + 0];
            s0sum   += perb[b * 3 + 1];
            snegsum += perb[b * 3 + 2];
        }
        out[0] = bsum * 0.25f;
        out[1] = s0sum * 0.25f;
        out[2] = snegsum * (1.0f / NEG) * 2.0f * 0.25f;
    }
}

extern "C" void kernel_launch(void* const* d_in, const int* in_sizes, int n_in,
                              void* d_out, int out_size, void* d_ws, size_t ws_size,
                              hipStream_t stream) {
    const float* v1   = (const float*)d_in[0];
    const float* v2   = (const float*)d_in[1];
    const float* img  = (const float*)d_in[2];
    const int*   negh = (const int*)d_in[3];
    const int*   negw = (const int*)d_in[4];
    float* out = (float*)d_out;
    float* ws  = (float*)d_ws;

    ushort* z2th    = (ushort*)(ws + OFF_Z2T);
    float* n1map    = ws + OFF_N1MAP;
    float* imgt4    = ws + OFF_IMGT4;
    float* partial  = ws + OFF_PARTIAL;
    float* partial2 = ws + OFF_PART2;
    float* perb     = ws + OFF_PERB;

    hipLaunchKernelGGL(k_prep_z2, dim3(B * 64), dim3(256), 0, stream, v2, z2th);
    hipLaunchKernelGGL(k_prep_z1, dim3(B * 16), dim3(256), 0, stream, v1, img, n1map, imgt4);
    hipLaunchKernelGGL(k_main, dim3(B * NCHUNK), dim3(256), 0, stream,
                       v1, negh, negw, z2th, n1map, imgt4, partial);
    hipLaunchKernelGGL(k_reduce1, dim3(B * NGRP), dim3(256), 0, stream, partial, partial2);
    hipLaunchKernelGGL(k_reduce2, dim3(B), dim3(256), 0, stream, partial2, n1map, perb);
    hipLaunchKernelGGL(k_final, dim3(1), dim3(64), 0, stream, perb, out);
}